// Round 1
// baseline (42.342 us; speedup 1.0000x reference)
//
#include <hip/hip_runtime.h>
#include <hip/hip_bf16.h>

// Lie (SE3) cumulative B-spline evaluation.
// out[b, p*K + k] = T0 * exp(w0(t_k)*log(T0^-1 T1)) * exp(w1*log(T1^-1 T2)) * exp(w2*log(T2^-1 T3))
// with padded pose sequence [first, poses..., last].

__device__ __forceinline__ void rel_log(const float* __restrict__ Ta,
                                        const float* __restrict__ Tb,
                                        float xi[6]) {
    // R = Ra^T Rb ; t = Ra^T (pb - pa)
    float R[9];
#pragma unroll
    for (int i = 0; i < 3; ++i)
#pragma unroll
        for (int j = 0; j < 3; ++j)
            R[i * 3 + j] = Ta[0 * 4 + i] * Tb[0 * 4 + j] +
                           Ta[1 * 4 + i] * Tb[1 * 4 + j] +
                           Ta[2 * 4 + i] * Tb[2 * 4 + j];
    float dx = Tb[3] - Ta[3], dy = Tb[7] - Ta[7], dz = Tb[11] - Ta[11];
    float t0 = Ta[0] * dx + Ta[4] * dy + Ta[8] * dz;
    float t1 = Ta[1] * dx + Ta[5] * dy + Ta[9] * dz;
    float t2 = Ta[2] * dx + Ta[6] * dy + Ta[10] * dz;

    float tr = R[0] + R[4] + R[8];
    float cos_th = 0.5f * (tr - 1.0f);
    cos_th = fminf(fmaxf(cos_th, -1.0f + 1e-6f), 1.0f - 1e-6f);
    float th = acosf(cos_th);
    float s = sinf(th);
    float vx = 0.5f * (R[7] - R[5]);
    float vy = 0.5f * (R[2] - R[6]);
    float vz = 0.5f * (R[3] - R[1]);
    float f = th / s;
    float ox = f * vx, oy = f * vy, oz = f * vz;
    float th2 = th * th;
    float D;
    if (th < 0.05f)
        D = 1.0f / 12.0f + th2 / 720.0f;
    else
        D = 1.0f / th2 - (1.0f + cos_th) / (2.0f * th * s);

    // Vinv = I - 0.5*hat(o) + D * (o o^T - |o|^2 I)
    float oo = ox * ox + oy * oy + oz * oz;
    float V00 = 1.0f + D * (ox * ox - oo);
    float V01 = 0.5f * oz + D * (ox * oy);
    float V02 = -0.5f * oy + D * (ox * oz);
    float V10 = -0.5f * oz + D * (ox * oy);
    float V11 = 1.0f + D * (oy * oy - oo);
    float V12 = 0.5f * ox + D * (oy * oz);
    float V20 = 0.5f * oy + D * (ox * oz);
    float V21 = -0.5f * ox + D * (oy * oz);
    float V22 = 1.0f + D * (oz * oz - oo);

    xi[0] = V00 * t0 + V01 * t1 + V02 * t2;
    xi[1] = V10 * t0 + V11 * t1 + V12 * t2;
    xi[2] = V20 * t0 + V21 * t1 + V22 * t2;
    xi[3] = ox; xi[4] = oy; xi[5] = oz;
}

__device__ __forceinline__ void se3_exp_scaled(float sc, const float xi[6],
                                               float R[9], float t[3]) {
    float nx = sc * xi[0], ny = sc * xi[1], nz = sc * xi[2];
    float ox = sc * xi[3], oy = sc * xi[4], oz = sc * xi[5];
    float th2 = ox * ox + oy * oy + oz * oz;
    float A, B, C;
    if (th2 < 1e-8f) {
        A = 1.0f - th2 * (1.0f / 6.0f);
        B = 0.5f - th2 * (1.0f / 24.0f);
        C = 1.0f / 6.0f - th2 * (1.0f / 120.0f);
    } else {
        float th = sqrtf(th2);
        float sn = sinf(th), cs = cosf(th);
        A = sn / th;
        B = (1.0f - cs) / th2;
        C = (th - sn) / (th2 * th);
    }
    float xx = ox * ox, yy = oy * oy, zz = oz * oz;
    float xy = ox * oy, xz = ox * oz, yz = oy * oz;
    // R = I + A*hat(o) + B*(o o^T - th2 I)
    R[0] = 1.0f + B * (xx - th2);
    R[1] = B * xy - A * oz;
    R[2] = B * xz + A * oy;
    R[3] = B * xy + A * oz;
    R[4] = 1.0f + B * (yy - th2);
    R[5] = B * yz - A * ox;
    R[6] = B * xz - A * oy;
    R[7] = B * yz + A * ox;
    R[8] = 1.0f + B * (zz - th2);
    // V = I + B*hat(o) + C*(o o^T - th2 I); t = V @ nu
    float V00 = 1.0f + C * (xx - th2);
    float V01 = C * xy - B * oz;
    float V02 = C * xz + B * oy;
    float V10 = C * xy + B * oz;
    float V11 = 1.0f + C * (yy - th2);
    float V12 = C * yz - B * ox;
    float V20 = C * xz - B * oy;
    float V21 = C * yz + B * ox;
    float V22 = 1.0f + C * (zz - th2);
    t[0] = V00 * nx + V01 * ny + V02 * nz;
    t[1] = V10 * nx + V11 * ny + V12 * nz;
    t[2] = V20 * nx + V21 * ny + V22 * nz;
}

__device__ __forceinline__ void compose(const float R1[9], const float t1[3],
                                        const float R2[9], const float t2[3],
                                        float Ro[9], float to[3]) {
#pragma unroll
    for (int i = 0; i < 3; ++i) {
#pragma unroll
        for (int j = 0; j < 3; ++j)
            Ro[i * 3 + j] = R1[i * 3 + 0] * R2[0 * 3 + j] +
                            R1[i * 3 + 1] * R2[1 * 3 + j] +
                            R1[i * 3 + 2] * R2[2 * 3 + j];
        to[i] = R1[i * 3 + 0] * t2[0] + R1[i * 3 + 1] * t2[1] +
                R1[i * 3 + 2] * t2[2] + t1[i];
    }
}

__global__ void __launch_bounds__(256)
lie_spline_kernel(const float* __restrict__ poses,
                  const float* __restrict__ timev,
                  float* __restrict__ out,
                  int Bsz, int n, int K, int total) {
    int g = blockIdx.x * blockDim.x + threadIdx.x;
    if (g >= total) return;
    int P = n - 1;
    int k = g % K;
    int bp = g / K;
    int p = bp % P;
    int b = bp / P;

    // padded index j maps to input index clamp(j-1, 0, n-1)
    int i0 = max(p - 1, 0);
    int i1 = p;
    int i2 = min(p + 1, n - 1);
    int i3 = min(p + 2, n - 1);

    const float* base = poses + (size_t)b * n * 16;
    const float* T0 = base + i0 * 16;
    const float* T1 = base + i1 * 16;
    const float* T2 = base + i2 * 16;
    const float* T3 = base + i3 * 16;

    float xi01[6], xi12[6], xi23[6];
    rel_log(T0, T1, xi01);
    rel_log(T1, T2, xi12);
    rel_log(T2, T3, xi23);

    float t = timev[k];
    float t2 = t * t, t3 = t2 * t;
    float w0 = (5.0f + 3.0f * t - 3.0f * t2 + t3) * (1.0f / 6.0f);
    float w1 = (1.0f + 3.0f * t + 3.0f * t2 - 2.0f * t3) * (1.0f / 6.0f);
    float w2 = t3 * (1.0f / 6.0f);

    float Ra[9], ta[3], Rb[9], tb[3], Rc[9], tc[3];
    se3_exp_scaled(w0, xi01, Ra, ta);
    se3_exp_scaled(w1, xi12, Rb, tb);
    se3_exp_scaled(w2, xi23, Rc, tc);

    float R0[9] = {T0[0], T0[1], T0[2], T0[4], T0[5], T0[6], T0[8], T0[9], T0[10]};
    float p0[3] = {T0[3], T0[7], T0[11]};

    float Rx[9], tx[3], Ry[9], ty[3], Rz[9], tz[3];
    compose(R0, p0, Ra, ta, Rx, tx);
    compose(Rx, tx, Rb, tb, Ry, ty);
    compose(Ry, ty, Rc, tc, Rz, tz);

    float4* o4 = (float4*)(out + (size_t)g * 16);
    o4[0] = make_float4(Rz[0], Rz[1], Rz[2], tz[0]);
    o4[1] = make_float4(Rz[3], Rz[4], Rz[5], tz[1]);
    o4[2] = make_float4(Rz[6], Rz[7], Rz[8], tz[2]);
    o4[3] = make_float4(0.0f, 0.0f, 0.0f, 1.0f);
}

extern "C" void kernel_launch(void* const* d_in, const int* in_sizes, int n_in,
                              void* d_out, int out_size, void* d_ws, size_t ws_size,
                              hipStream_t stream) {
    const float* poses = (const float*)d_in[0];
    const float* timev = (const float*)d_in[1];
    float* out = (float*)d_out;

    int K = in_sizes[1];                 // 64
    int S = in_sizes[0] / 16;            // B * n
    int Q = out_size / (16 * K);         // B * (n-1)
    int Bsz = S - Q;                     // B
    int n = S / Bsz;                     // n

    int total = Bsz * (n - 1) * K;
    int block = 256;
    int grid = (total + block - 1) / block;
    hipLaunchKernelGGL(lie_spline_kernel, dim3(grid), dim3(block), 0, stream,
                       poses, timev, out, Bsz, n, K, total);
}

// Round 2
// 34.784 us; speedup vs baseline: 1.2173x; 1.2173x over previous
//
#include <hip/hip_runtime.h>
#include <hip/hip_bf16.h>

// Lie (SE3) cumulative B-spline evaluation, two-phase:
//  K1: rel[j] = log(Q[j]^-1 Q[j+1]) for j in [0, n], Q = padded poses  (B*513 threads)
//  K2: out[b,p,k] = T0 * exp(w0*rel[p]) * exp(w1*rel[p+1]) * exp(w2*rel[p+2])

__device__ __forceinline__ float frcp(float x) { return __builtin_amdgcn_rcpf(x); }

__device__ __forceinline__ void rel_log(const float* __restrict__ Ta,
                                        const float* __restrict__ Tb,
                                        float xi[6]) {
    // R = Ra^T Rb ; t = Ra^T (pb - pa)
    float R[9];
#pragma unroll
    for (int i = 0; i < 3; ++i)
#pragma unroll
        for (int j = 0; j < 3; ++j)
            R[i * 3 + j] = Ta[0 * 4 + i] * Tb[0 * 4 + j] +
                           Ta[1 * 4 + i] * Tb[1 * 4 + j] +
                           Ta[2 * 4 + i] * Tb[2 * 4 + j];
    float dx = Tb[3] - Ta[3], dy = Tb[7] - Ta[7], dz = Tb[11] - Ta[11];
    float t0 = Ta[0] * dx + Ta[4] * dy + Ta[8] * dz;
    float t1 = Ta[1] * dx + Ta[5] * dy + Ta[9] * dz;
    float t2 = Ta[2] * dx + Ta[6] * dy + Ta[10] * dz;

    float tr = R[0] + R[4] + R[8];
    float cos_th = 0.5f * (tr - 1.0f);
    cos_th = fminf(fmaxf(cos_th, -1.0f + 1e-6f), 1.0f - 1e-6f);
    float th = acosf(cos_th);
    float s = sinf(th);
    float vx = 0.5f * (R[7] - R[5]);
    float vy = 0.5f * (R[2] - R[6]);
    float vz = 0.5f * (R[3] - R[1]);
    float f = th / s;
    float ox = f * vx, oy = f * vy, oz = f * vz;
    float th2 = th * th;
    float D;
    if (th < 0.05f)
        D = 1.0f / 12.0f + th2 / 720.0f;
    else
        D = 1.0f / th2 - (1.0f + cos_th) / (2.0f * th * s);

    // Vinv = I - 0.5*hat(o) + D * (o o^T - |o|^2 I)
    float oo = ox * ox + oy * oy + oz * oz;
    float V00 = 1.0f + D * (ox * ox - oo);
    float V01 = 0.5f * oz + D * (ox * oy);
    float V02 = -0.5f * oy + D * (ox * oz);
    float V10 = -0.5f * oz + D * (ox * oy);
    float V11 = 1.0f + D * (oy * oy - oo);
    float V12 = 0.5f * ox + D * (oy * oz);
    float V20 = 0.5f * oy + D * (ox * oz);
    float V21 = -0.5f * ox + D * (oy * oz);
    float V22 = 1.0f + D * (oz * oz - oo);

    xi[0] = V00 * t0 + V01 * t1 + V02 * t2;
    xi[1] = V10 * t0 + V11 * t1 + V12 * t2;
    xi[2] = V20 * t0 + V21 * t1 + V22 * t2;
    xi[3] = ox; xi[4] = oy; xi[5] = oz;
}

// Kernel 1: one thread per (b, j), j in [0, n] inclusive -> n+1 logs per batch.
__global__ void __launch_bounds__(256)
rel_log_kernel(const float* __restrict__ poses, float* __restrict__ rel,
               int n, int total) {
    int idx = blockIdx.x * blockDim.x + threadIdx.x;
    if (idx >= total) return;
    int m = n + 1;
    int j = idx % m;
    int b = idx / m;
    // Q[j] = poses[clamp(j-1, 0, n-1)]
    int ia = max(j - 1, 0);
    int ib = min(j, n - 1);
    const float* base = poses + (size_t)b * n * 16;
    float xi[6];
    rel_log(base + ia * 16, base + ib * 16, xi);
    float* o = rel + (size_t)idx * 8;
    float4* o4 = (float4*)o;
    o4[0] = make_float4(xi[0], xi[1], xi[2], xi[3]);
    o4[1] = make_float4(xi[4], xi[5], 0.0f, 0.0f);
}

__device__ __forceinline__ void se3_exp_scaled(float sc, const float xi[6],
                                               float R[9], float t[3]) {
    float nx = sc * xi[0], ny = sc * xi[1], nz = sc * xi[2];
    float ox = sc * xi[3], oy = sc * xi[4], oz = sc * xi[5];
    float th2 = ox * ox + oy * oy + oz * oz;
    float A, B, C;
    if (th2 < 1e-8f) {
        A = 1.0f - th2 * (1.0f / 6.0f);
        B = 0.5f - th2 * (1.0f / 24.0f);
        C = 1.0f / 6.0f - th2 * (1.0f / 120.0f);
    } else {
        float th = sqrtf(th2);
        float sn, cs;
        __sincosf(th, &sn, &cs);
        float r = frcp(th);
        float r2 = r * r;
        A = sn * r;
        B = (1.0f - cs) * r2;
        C = (th - sn) * r2 * r;
    }
    float xx = ox * ox, yy = oy * oy, zz = oz * oz;
    float xy = ox * oy, xz = ox * oz, yz = oy * oz;
    R[0] = 1.0f + B * (xx - th2);
    R[1] = B * xy - A * oz;
    R[2] = B * xz + A * oy;
    R[3] = B * xy + A * oz;
    R[4] = 1.0f + B * (yy - th2);
    R[5] = B * yz - A * ox;
    R[6] = B * xz - A * oy;
    R[7] = B * yz + A * ox;
    R[8] = 1.0f + B * (zz - th2);
    float V00 = 1.0f + C * (xx - th2);
    float V01 = C * xy - B * oz;
    float V02 = C * xz + B * oy;
    float V10 = C * xy + B * oz;
    float V11 = 1.0f + C * (yy - th2);
    float V12 = C * yz - B * ox;
    float V20 = C * xz - B * oy;
    float V21 = C * yz + B * ox;
    float V22 = 1.0f + C * (zz - th2);
    t[0] = V00 * nx + V01 * ny + V02 * nz;
    t[1] = V10 * nx + V11 * ny + V12 * nz;
    t[2] = V20 * nx + V21 * ny + V22 * nz;
}

__device__ __forceinline__ void compose(const float R1[9], const float t1[3],
                                        const float R2[9], const float t2[3],
                                        float Ro[9], float to[3]) {
#pragma unroll
    for (int i = 0; i < 3; ++i) {
#pragma unroll
        for (int j = 0; j < 3; ++j)
            Ro[i * 3 + j] = R1[i * 3 + 0] * R2[0 * 3 + j] +
                            R1[i * 3 + 1] * R2[1 * 3 + j] +
                            R1[i * 3 + 2] * R2[2 * 3 + j];
        to[i] = R1[i * 3 + 0] * t2[0] + R1[i * 3 + 1] * t2[1] +
                R1[i * 3 + 2] * t2[2] + t1[i];
    }
}

// Kernel 2: one thread per (b, p, k).
__global__ void __launch_bounds__(256)
spline_eval_kernel(const float* __restrict__ poses,
                   const float* __restrict__ rel,
                   const float* __restrict__ timev,
                   float* __restrict__ out,
                   int n, int K, int total) {
    int g = blockIdx.x * blockDim.x + threadIdx.x;
    if (g >= total) return;
    int P = n - 1;
    int k = g % K;
    int bp = g / K;
    int p = bp % P;
    int b = bp / P;

    int m = n + 1;
    const float4* relv = (const float4*)(rel + (size_t)(b * m + p) * 8);
    float4 a0 = relv[0], a1 = relv[1];
    float4 b0 = relv[2], b1 = relv[3];
    float4 c0 = relv[4], c1 = relv[5];
    float xi01[6] = {a0.x, a0.y, a0.z, a0.w, a1.x, a1.y};
    float xi12[6] = {b0.x, b0.y, b0.z, b0.w, b1.x, b1.y};
    float xi23[6] = {c0.x, c0.y, c0.z, c0.w, c1.x, c1.y};

    float t = timev[k];
    float t2 = t * t, t3 = t2 * t;
    float w0 = (5.0f + 3.0f * t - 3.0f * t2 + t3) * (1.0f / 6.0f);
    float w1 = (1.0f + 3.0f * t + 3.0f * t2 - 2.0f * t3) * (1.0f / 6.0f);
    float w2 = t3 * (1.0f / 6.0f);

    float Ra[9], ta[3], Rb[9], tb[3], Rc[9], tc[3];
    se3_exp_scaled(w0, xi01, Ra, ta);
    se3_exp_scaled(w1, xi12, Rb, tb);
    se3_exp_scaled(w2, xi23, Rc, tc);

    int i0 = max(p - 1, 0);
    const float* T0 = poses + ((size_t)b * n + i0) * 16;
    float R0[9] = {T0[0], T0[1], T0[2], T0[4], T0[5], T0[6], T0[8], T0[9], T0[10]};
    float p0[3] = {T0[3], T0[7], T0[11]};

    float Rx[9], tx[3], Ry[9], ty[3], Rz[9], tz[3];
    compose(R0, p0, Ra, ta, Rx, tx);
    compose(Rx, tx, Rb, tb, Ry, ty);
    compose(Ry, ty, Rc, tc, Rz, tz);

    float4* o4 = (float4*)(out + (size_t)g * 16);
    o4[0] = make_float4(Rz[0], Rz[1], Rz[2], tz[0]);
    o4[1] = make_float4(Rz[3], Rz[4], Rz[5], tz[1]);
    o4[2] = make_float4(Rz[6], Rz[7], Rz[8], tz[2]);
    o4[3] = make_float4(0.0f, 0.0f, 0.0f, 1.0f);
}

// Fallback monolithic kernel (used only if workspace is too small).
__global__ void __launch_bounds__(256)
lie_spline_mono(const float* __restrict__ poses,
                const float* __restrict__ timev,
                float* __restrict__ out,
                int n, int K, int total) {
    int g = blockIdx.x * blockDim.x + threadIdx.x;
    if (g >= total) return;
    int P = n - 1;
    int k = g % K;
    int bp = g / K;
    int p = bp % P;
    int b = bp / P;
    int i0 = max(p - 1, 0);
    int i1 = p;
    int i2 = min(p + 1, n - 1);
    int i3 = min(p + 2, n - 1);
    const float* base = poses + (size_t)b * n * 16;
    const float *T0 = base + i0 * 16, *T1 = base + i1 * 16;
    const float *T2 = base + i2 * 16, *T3 = base + i3 * 16;
    float xi01[6], xi12[6], xi23[6];
    rel_log(T0, T1, xi01);
    rel_log(T1, T2, xi12);
    rel_log(T2, T3, xi23);
    float t = timev[k];
    float t2 = t * t, t3 = t2 * t;
    float w0 = (5.0f + 3.0f * t - 3.0f * t2 + t3) * (1.0f / 6.0f);
    float w1 = (1.0f + 3.0f * t + 3.0f * t2 - 2.0f * t3) * (1.0f / 6.0f);
    float w2 = t3 * (1.0f / 6.0f);
    float Ra[9], ta[3], Rb[9], tb[3], Rc[9], tc[3];
    se3_exp_scaled(w0, xi01, Ra, ta);
    se3_exp_scaled(w1, xi12, Rb, tb);
    se3_exp_scaled(w2, xi23, Rc, tc);
    float R0[9] = {T0[0], T0[1], T0[2], T0[4], T0[5], T0[6], T0[8], T0[9], T0[10]};
    float p0[3] = {T0[3], T0[7], T0[11]};
    float Rx[9], tx[3], Ry[9], ty[3], Rz[9], tz[3];
    compose(R0, p0, Ra, ta, Rx, tx);
    compose(Rx, tx, Rb, tb, Ry, ty);
    compose(Ry, ty, Rc, tc, Rz, tz);
    float4* o4 = (float4*)(out + (size_t)g * 16);
    o4[0] = make_float4(Rz[0], Rz[1], Rz[2], tz[0]);
    o4[1] = make_float4(Rz[3], Rz[4], Rz[5], tz[1]);
    o4[2] = make_float4(Rz[6], Rz[7], Rz[8], tz[2]);
    o4[3] = make_float4(0.0f, 0.0f, 0.0f, 1.0f);
}

extern "C" void kernel_launch(void* const* d_in, const int* in_sizes, int n_in,
                              void* d_out, int out_size, void* d_ws, size_t ws_size,
                              hipStream_t stream) {
    const float* poses = (const float*)d_in[0];
    const float* timev = (const float*)d_in[1];
    float* out = (float*)d_out;

    int K = in_sizes[1];                 // 64
    int S = in_sizes[0] / 16;            // B * n
    int Q = out_size / (16 * K);         // B * (n-1)
    int Bsz = S - Q;                     // B
    int n = S / Bsz;                     // n

    int P = n - 1;
    int total = Bsz * P * K;
    int block = 256;

    size_t rel_bytes = (size_t)Bsz * (n + 1) * 8 * sizeof(float);
    if (ws_size >= rel_bytes) {
        float* rel = (float*)d_ws;
        int total1 = Bsz * (n + 1);
        hipLaunchKernelGGL(rel_log_kernel, dim3((total1 + block - 1) / block),
                           dim3(block), 0, stream, poses, rel, n, total1);
        hipLaunchKernelGGL(spline_eval_kernel, dim3((total + block - 1) / block),
                           dim3(block), 0, stream, poses, rel, timev, out,
                           n, K, total);
    } else {
        hipLaunchKernelGGL(lie_spline_mono, dim3((total + block - 1) / block),
                           dim3(block), 0, stream, poses, timev, out,
                           n, K, total);
    }
}